// Round 4
// baseline (898.339 us; speedup 1.0000x reference)
//
#include <hip/hip_runtime.h>

// CPQuadRankLayer: B=64, N=1024, C=4, R=64, D=128, fp32.
//   projected[b,n,c,r] = sum_i x[b,n,c,i] * factors[c,n,r,i]
//   p = projected * rsqrt(mean_r(projected^2) + 1e-6)
//   merged[b,n,r] = p0*p1*p2*p3 * gain[n]
//   out[b,n,o] = sum_r merged[b,n,r]*factor_out[n,r,o] + 0.25*sum_c x[b,n,c,o]
//
// R4 = R3 register-tiled GEMM (block per n; wave=c; 8x8 lane tile; DMA-staged
// dbuf LDS; XOR slot swizzle) plus:
//  (1) launch_bounds(256,3): 3 blocks/CU (R3 ran at 2; all pipes <45% busy).
//  (2) residual harvested from the LDS x region during phase 1 (quarter-wave
//      masked reads at the one chunk holding this thread's o-quad) -> the
//      128MB epilogue x re-read (L3-missed, measured in FETCH_SIZE) is gone.
// R2 lesson retained: every array indexed only by compile-time constants.

constexpr int Nn = 1024;
constexpr int Cc = 4;
constexpr int Dd = 128;
constexpr int Rr = 64;
constexpr int IC = 8;             // i-chunk depth
constexpr int NCH = Dd / IC;      // 16 chunks

typedef __attribute__((address_space(3))) float lds_float;
typedef __attribute__((address_space(1))) const float gbl_float;

__device__ __forceinline__ void ald16(const float* g, const float* l) {
  __builtin_amdgcn_global_load_lds((gbl_float*)g,
                                   (lds_float*)(uint32_t)(uintptr_t)l,
                                   16, 0, 0);
}

__device__ __forceinline__ int row_of_slot(int s) {
  const int a = s >> 3;
  return 8 * a + ((s & 7) ^ a);   // involution: slot(8a+j)=8a+(j^a)
}

__global__ __launch_bounds__(256, 3)
void cpquad_kernel(const float* __restrict__ x,
                   const float* __restrict__ factors,
                   const float* __restrict__ factor_out,
                   const float* __restrict__ gain,
                   float* __restrict__ out) {
  // f region [0,4096): (p*4+c)*512 + slot*8 + i ; x region [4096,8192) same.
  // Reused flat as factor_out[n] ([64r][128o]) in phase 4.
  __shared__ alignas(16) float Sbuf[8192];
  __shared__ alignas(16) float pT[Rr][72];   // 2-way read banks; write 8-way (3%, measured ok)

  const int n   = blockIdx.x;
  const int tid = threadIdx.x;
  const int c   = tid >> 6;       // wave = child
  const int l   = tid & 63;
  const int bg  = l & 7;          // b-group
  const int rg  = l >> 3;         // r-group (o-group in phase 4)
  const int h   = l & 1;

  const int s0 = l >> 1, s1 = 32 + (l >> 1);
  const int r0 = row_of_slot(s0), r1 = row_of_slot(s1);
  const float* fcn = factors + (((size_t)c * Nn + n) * Rr) * Dd;
  const float* fsrc0 = fcn + r0 * Dd + h * 4;
  const float* fsrc1 = fcn + r1 * Dd + h * 4;
  const float* xsrc0 = x + (((size_t)r0 * Nn + n) * Cc + c) * Dd + h * 4;
  const float* xsrc1 = x + (((size_t)r1 * Nn + n) * Cc + c) * Dd + h * 4;

  // ---- prologue: stage chunk 0 ----
  {
    float* fw = Sbuf + c * 512;
    float* xw = Sbuf + 4096 + c * 512;
    ald16(fsrc0, fw);  ald16(fsrc1, fw + 256);
    ald16(xsrc0, xw);  ald16(xsrc1, xw + 256);
  }

  float acc[8][8];
#pragma unroll
  for (int kk = 0; kk < 8; ++kk)
#pragma unroll
    for (int jj = 0; jj < 8; ++jj) acc[kk][jj] = 0.0f;

  int fof[8], xof[8];
#pragma unroll
  for (int t = 0; t < 8; ++t) {
    fof[t] = (8 * rg + (t ^ rg)) * 8;
    xof[t] = (8 * bg + (t ^ bg)) * 8;
  }

  // residual harvest state: this thread's phase-4 o-quad o0 = c*32 + rg*4
  // lives in i-chunk (o0>>3) = 4c + (rg>>1), float offset (rg&1)*4.
  const int harvest_ch = 4 * c + (rg >> 1);
  const int hoff = (rg & 1) * 4;
  float4 res[8];
#pragma unroll
  for (int kk = 0; kk < 8; ++kk) res[kk] = make_float4(0.f, 0.f, 0.f, 0.f);

  __syncthreads();  // chunk-0 DMA drained

  // ---------------- Phase 1: projection GEMM ----------------
#pragma unroll 1
  for (int ch = 0; ch < NCH; ++ch) {
    const int p = ch & 1;
    if (ch + 1 < NCH) {
      const int i0 = (ch + 1) * IC;
      float* fw = Sbuf + ((p ^ 1) * 4 + c) * 512;
      float* xw = Sbuf + 4096 + ((p ^ 1) * 4 + c) * 512;
      ald16(fsrc0 + i0, fw);  ald16(fsrc1 + i0, fw + 256);
      ald16(xsrc0 + i0, xw);  ald16(xsrc1 + i0, xw + 256);
    }
    const float* fr = Sbuf + (p * 4 + c) * 512;
    const float* xr = Sbuf + 4096 + (p * 4 + c) * 512;
#pragma unroll
    for (int hh = 0; hh < 2; ++hh) {
      float4 fv[8], xv[8];
#pragma unroll
      for (int jj = 0; jj < 8; ++jj)
        fv[jj] = *(const float4*)(fr + fof[jj] + hh * 4);
#pragma unroll
      for (int kk = 0; kk < 8; ++kk)
        xv[kk] = *(const float4*)(xr + xof[kk] + hh * 4);
#pragma unroll
      for (int kk = 0; kk < 8; ++kk)
#pragma unroll
        for (int jj = 0; jj < 8; ++jj) {
          float a = acc[kk][jj];
          a = fmaf(xv[kk].x, fv[jj].x, a);
          a = fmaf(xv[kk].y, fv[jj].y, a);
          a = fmaf(xv[kk].z, fv[jj].z, a);
          a = fmaf(xv[kk].w, fv[jj].w, a);
          acc[kk][jj] = a;
        }
    }
    // ---- residual harvest (quarter-wave active at its chunk) ----
    if (ch == harvest_ch) {
      const float* xbase = Sbuf + 4096 + p * 4 * 512;
#pragma unroll
      for (int kk = 0; kk < 8; ++kk) {
        const int slot = 8 * bg + (kk ^ bg);
#pragma unroll
        for (int cc = 0; cc < 4; ++cc) {
          const float4 v = *(const float4*)(xbase + cc * 512 + slot * 8 + hoff);
          res[kk].x += v.x;  res[kk].y += v.y;
          res[kk].z += v.z;  res[kk].w += v.w;
        }
      }
    }
    __syncthreads();  // buf p consumed; next iter's DMA may overwrite it
  }

  // ---- stage factor_out[n] (32 KiB flat) into Sbuf ----
  {
    const float* fog = factor_out + (size_t)n * Rr * Dd;
#pragma unroll
    for (int k = 0; k < 8; ++k) {
      const int sec = k * 4 + c;                    // wave-uniform
      ald16(fog + sec * 256 + l * 4, Sbuf + sec * 256);
    }
  }

  // ---------------- Phase 2: RMSNorm over r ----------------
  float scale[8];
  {
    const float g = gain[n];
#pragma unroll
    for (int kk = 0; kk < 8; ++kk) {
      float s = 0.0f;
#pragma unroll
      for (int jj = 0; jj < 8; ++jj) s = fmaf(acc[kk][jj], acc[kk][jj], s);
      s += __shfl_xor(s, 8);
      s += __shfl_xor(s, 16);
      s += __shfl_xor(s, 32);
      float sc = 1.0f / sqrtf(s * (1.0f / 64.0f) + 1e-6f);
      if (c == 0) sc *= g;
      scale[kk] = sc;
    }
  }

  // ---------------- Phase 3: quartic product into pT[r][b] --------------
#pragma unroll
  for (int w = 0; w < 4; ++w) {
    if (c == w) {
#pragma unroll
      for (int jj = 0; jj < 8; ++jj) {
        float4 lo, hi;
        lo.x = acc[0][jj] * scale[0];  lo.y = acc[1][jj] * scale[1];
        lo.z = acc[2][jj] * scale[2];  lo.w = acc[3][jj] * scale[3];
        hi.x = acc[4][jj] * scale[4];  hi.y = acc[5][jj] * scale[5];
        hi.z = acc[6][jj] * scale[6];  hi.w = acc[7][jj] * scale[7];
        float4* dst = (float4*)&pT[8 * rg + jj][8 * bg];
        if (w == 0) {
          dst[0] = lo;  dst[1] = hi;
        } else {
          float4 a0 = dst[0], a1 = dst[1];
          a0.x *= lo.x; a0.y *= lo.y; a0.z *= lo.z; a0.w *= lo.w;
          a1.x *= hi.x; a1.y *= hi.y; a1.z *= hi.z; a1.w *= hi.w;
          dst[0] = a0;  dst[1] = a1;
        }
      }
    }
    __syncthreads();  // order passes; drains fo DMA by the last one
  }

  // ---------------- Phase 4: output projection ----------------
  const int o0 = c * 32 + rg * 4;
  float4 a2[8];
#pragma unroll
  for (int kk = 0; kk < 8; ++kk) a2[kk] = make_float4(0.f, 0.f, 0.f, 0.f);

#pragma unroll 4
  for (int r = 0; r < Rr; ++r) {
    const float4 m0 = *(const float4*)&pT[r][8 * bg];
    const float4 m1 = *(const float4*)&pT[r][8 * bg + 4];
    const float4 f  = *(const float4*)(Sbuf + r * Dd + o0);
    a2[0].x = fmaf(m0.x, f.x, a2[0].x); a2[0].y = fmaf(m0.x, f.y, a2[0].y);
    a2[0].z = fmaf(m0.x, f.z, a2[0].z); a2[0].w = fmaf(m0.x, f.w, a2[0].w);
    a2[1].x = fmaf(m0.y, f.x, a2[1].x); a2[1].y = fmaf(m0.y, f.y, a2[1].y);
    a2[1].z = fmaf(m0.y, f.z, a2[1].z); a2[1].w = fmaf(m0.y, f.w, a2[1].w);
    a2[2].x = fmaf(m0.z, f.x, a2[2].x); a2[2].y = fmaf(m0.z, f.y, a2[2].y);
    a2[2].z = fmaf(m0.z, f.z, a2[2].z); a2[2].w = fmaf(m0.z, f.w, a2[2].w);
    a2[3].x = fmaf(m0.w, f.x, a2[3].x); a2[3].y = fmaf(m0.w, f.y, a2[3].y);
    a2[3].z = fmaf(m0.w, f.z, a2[3].z); a2[3].w = fmaf(m0.w, f.w, a2[3].w);
    a2[4].x = fmaf(m1.x, f.x, a2[4].x); a2[4].y = fmaf(m1.x, f.y, a2[4].y);
    a2[4].z = fmaf(m1.x, f.z, a2[4].z); a2[4].w = fmaf(m1.x, f.w, a2[4].w);
    a2[5].x = fmaf(m1.y, f.x, a2[5].x); a2[5].y = fmaf(m1.y, f.y, a2[5].y);
    a2[5].z = fmaf(m1.y, f.z, a2[5].z); a2[5].w = fmaf(m1.y, f.w, a2[5].w);
    a2[6].x = fmaf(m1.z, f.x, a2[6].x); a2[6].y = fmaf(m1.z, f.y, a2[6].y);
    a2[6].z = fmaf(m1.z, f.z, a2[6].z); a2[6].w = fmaf(m1.z, f.w, a2[6].w);
    a2[7].x = fmaf(m1.w, f.x, a2[7].x); a2[7].y = fmaf(m1.w, f.y, a2[7].y);
    a2[7].z = fmaf(m1.w, f.z, a2[7].z); a2[7].w = fmaf(m1.w, f.w, a2[7].w);
  }

  // ---------------- epilogue: residual (from harvest regs) + store ------
#pragma unroll
  for (int kk = 0; kk < 8; ++kk) {
    const int b = 8 * bg + kk;
    float4 v;
    v.x = a2[kk].x + 0.25f * res[kk].x;
    v.y = a2[kk].y + 0.25f * res[kk].y;
    v.z = a2[kk].z + 0.25f * res[kk].z;
    v.w = a2[kk].w + 0.25f * res[kk].w;
    *(float4*)(out + ((size_t)b * Nn + n) * Dd + o0) = v;
  }
}

extern "C" void kernel_launch(void* const* d_in, const int* in_sizes, int n_in,
                              void* d_out, int out_size, void* d_ws, size_t ws_size,
                              hipStream_t stream) {
  const float* x          = (const float*)d_in[0];
  const float* factors    = (const float*)d_in[1];
  const float* factor_out = (const float*)d_in[2];
  const float* gain       = (const float*)d_in[3];
  float* out              = (float*)d_out;
  hipLaunchKernelGGL(cpquad_kernel, dim3(Nn), dim3(256), 0, stream,
                     x, factors, factor_out, gain, out);
}

// Round 6
// 383.272 us; speedup vs baseline: 2.3439x; 2.3439x over previous
//
#include <hip/hip_runtime.h>

// CPQuadRankLayer: B=64, N=1024, C=4, R=64, D=128, fp32.
//   projected[b,n,c,r] = sum_i x[b,n,c,i] * factors[c,n,r,i]
//   p = projected * rsqrt(mean_r(projected^2) + 1e-6)
//   merged[b,n,r] = p0*p1*p2*p3 * gain[n]
//   out[b,n,o] = sum_r merged[b,n,r]*factor_out[n,r,o] + 0.25*sum_c x[b,n,c,o]
//
// R6 = R5 with the vmcnt arithmetic FIXED: each chunk issues 4 DMAs (not 8),
// so the partial wait must be vmcnt(4) -- R5's vmcnt(8) was a no-op and the
// kernel read unwritten LDS (absmax 10). sched_barrier(0) on BOTH sides of
// the wait pins DMA-issue above / ds_read below.
// Phase-1 LDS regions are wave-private -> no barriers in the K-loop; next
// chunk's global_load_lds stays in flight across chunk boundaries.
// R4 lesson: launch_bounds(256,2) only (higher min-occupancy spills acc).
// R2 lesson: private arrays indexed by compile-time constants only.

constexpr int Nn = 1024;
constexpr int Cc = 4;
constexpr int Dd = 128;
constexpr int Rr = 64;
constexpr int IC = 8;             // i-chunk depth
constexpr int NCH = Dd / IC;      // 16 chunks

typedef __attribute__((address_space(3))) float lds_float;
typedef __attribute__((address_space(1))) const float gbl_float;

__device__ __forceinline__ void ald16(const float* g, const float* l) {
  __builtin_amdgcn_global_load_lds((gbl_float*)g,
                                   (lds_float*)(uint32_t)(uintptr_t)l,
                                   16, 0, 0);
}

// s_waitcnt imm (gfx9/CDNA): vmcnt[3:0]=bits[3:0], vmcnt[5:4]=bits[15:14],
// expcnt=bits[6:4], lgkmcnt=bits[11:8]. exp=7/lgkm=15 masked; vm counted.
__device__ __forceinline__ void wait_vm4() {
  __builtin_amdgcn_sched_barrier(0);    // DMAs must issue before this point
  __builtin_amdgcn_s_waitcnt(0x0F74);   // vmcnt(4): current chunk's 4 done
  __builtin_amdgcn_sched_barrier(0);    // ds_reads must not hoist above
}
__device__ __forceinline__ void wait_vm0() {
  __builtin_amdgcn_sched_barrier(0);
  __builtin_amdgcn_s_waitcnt(0x0F70);   // vmcnt(0)
  __builtin_amdgcn_sched_barrier(0);
}

__device__ __forceinline__ int row_of_slot(int s) {
  const int a = s >> 3;
  return 8 * a + ((s & 7) ^ a);   // involution: slot(8a+j)=8a+(j^a)
}

__global__ __launch_bounds__(256, 2)
void cpquad_kernel(const float* __restrict__ x,
                   const float* __restrict__ factors,
                   const float* __restrict__ factor_out,
                   const float* __restrict__ gain,
                   float* __restrict__ out) {
  // f region [0,4096): (p*4+c)*512 + slot*8 + i ; x region [4096,8192) same.
  // Reused flat as factor_out[n] ([64r][128o]) in phase 4.
  __shared__ alignas(16) float Sbuf[8192];
  __shared__ alignas(16) float pT[Rr][72];

  const int n   = blockIdx.x;
  const int tid = threadIdx.x;
  const int c   = tid >> 6;       // wave = child
  const int l   = tid & 63;
  const int bg  = l & 7;          // b-group
  const int rg  = l >> 3;         // r-group (o-group in phase 4)
  const int h   = l & 1;

  const int s0 = l >> 1, s1 = 32 + (l >> 1);
  const int r0 = row_of_slot(s0), r1 = row_of_slot(s1);
  const float* fcn = factors + (((size_t)c * Nn + n) * Rr) * Dd;
  const float* fsrc0 = fcn + r0 * Dd + h * 4;
  const float* fsrc1 = fcn + r1 * Dd + h * 4;
  const float* xsrc0 = x + (((size_t)r0 * Nn + n) * Cc + c) * Dd + h * 4;
  const float* xsrc1 = x + (((size_t)r1 * Nn + n) * Cc + c) * Dd + h * 4;

  // ---- prologue: stage chunk 0 (4 DMAs, stay in flight) ----
  {
    float* fw = Sbuf + c * 512;
    float* xw = Sbuf + 4096 + c * 512;
    ald16(fsrc0, fw);  ald16(fsrc1, fw + 256);
    ald16(xsrc0, xw);  ald16(xsrc1, xw + 256);
  }

  float acc[8][8];
#pragma unroll
  for (int kk = 0; kk < 8; ++kk)
#pragma unroll
    for (int jj = 0; jj < 8; ++jj) acc[kk][jj] = 0.0f;

  int fof[8], xof[8];
#pragma unroll
  for (int t = 0; t < 8; ++t) {
    fof[t] = (8 * rg + (t ^ rg)) * 8;
    xof[t] = (8 * bg + (t ^ bg)) * 8;
  }

  // ---------------- Phase 1: projection GEMM (NO barriers) --------------
#pragma unroll 1
  for (int ch = 0; ch < NCH; ++ch) {
    const int p = ch & 1;
    if (ch + 1 < NCH) {
      const int i0 = (ch + 1) * IC;
      float* fw = Sbuf + ((p ^ 1) * 4 + c) * 512;
      float* xw = Sbuf + 4096 + ((p ^ 1) * 4 + c) * 512;
      ald16(fsrc0 + i0, fw);  ald16(fsrc1 + i0, fw + 256);
      ald16(xsrc0 + i0, xw);  ald16(xsrc1 + i0, xw + 256);
      wait_vm4();   // chunk ch's 4 DMAs complete; ch+1's 4 stay in flight
    } else {
      wait_vm0();   // final chunk: drain
    }
    const float* fr = Sbuf + (p * 4 + c) * 512;
    const float* xr = Sbuf + 4096 + (p * 4 + c) * 512;
#pragma unroll
    for (int hh = 0; hh < 2; ++hh) {
      float4 fv[8], xv[8];
#pragma unroll
      for (int jj = 0; jj < 8; ++jj)
        fv[jj] = *(const float4*)(fr + fof[jj] + hh * 4);
#pragma unroll
      for (int kk = 0; kk < 8; ++kk)
        xv[kk] = *(const float4*)(xr + xof[kk] + hh * 4);
#pragma unroll
      for (int kk = 0; kk < 8; ++kk)
#pragma unroll
        for (int jj = 0; jj < 8; ++jj) {
          float a = acc[kk][jj];
          a = fmaf(xv[kk].x, fv[jj].x, a);
          a = fmaf(xv[kk].y, fv[jj].y, a);
          a = fmaf(xv[kk].z, fv[jj].z, a);
          a = fmaf(xv[kk].w, fv[jj].w, a);
          acc[kk][jj] = a;
        }
    }
    // no __syncthreads: both staging buffers are this wave's own.
  }

  __syncthreads();  // ALL waves done with Sbuf before fo staging reuses it

  // ---- stage factor_out[n] (32 KiB flat) into Sbuf ----
  {
    const float* fog = factor_out + (size_t)n * Rr * Dd;
#pragma unroll
    for (int k = 0; k < 8; ++k) {
      const int sec = k * 4 + c;                    // wave-uniform
      ald16(fog + sec * 256 + l * 4, Sbuf + sec * 256);
    }
  }

  // ---------------- Phase 2: RMSNorm over r ----------------
  float scale[8];
  {
    const float g = gain[n];
#pragma unroll
    for (int kk = 0; kk < 8; ++kk) {
      float s = 0.0f;
#pragma unroll
      for (int jj = 0; jj < 8; ++jj) s = fmaf(acc[kk][jj], acc[kk][jj], s);
      s += __shfl_xor(s, 8);
      s += __shfl_xor(s, 16);
      s += __shfl_xor(s, 32);
      float sc = 1.0f / sqrtf(s * (1.0f / 64.0f) + 1e-6f);
      if (c == 0) sc *= g;
      scale[kk] = sc;
    }
  }

  // ---------------- Phase 3: quartic product into pT[r][b] --------------
#pragma unroll
  for (int w = 0; w < 4; ++w) {
    if (c == w) {
#pragma unroll
      for (int jj = 0; jj < 8; ++jj) {
        float4 lo, hi;
        lo.x = acc[0][jj] * scale[0];  lo.y = acc[1][jj] * scale[1];
        lo.z = acc[2][jj] * scale[2];  lo.w = acc[3][jj] * scale[3];
        hi.x = acc[4][jj] * scale[4];  hi.y = acc[5][jj] * scale[5];
        hi.z = acc[6][jj] * scale[6];  hi.w = acc[7][jj] * scale[7];
        float4* dst = (float4*)&pT[8 * rg + jj][8 * bg];
        if (w == 0) {
          dst[0] = lo;  dst[1] = hi;
        } else {
          float4 a0 = dst[0], a1 = dst[1];
          a0.x *= lo.x; a0.y *= lo.y; a0.z *= lo.z; a0.w *= lo.w;
          a1.x *= hi.x; a1.y *= hi.y; a1.z *= hi.z; a1.w *= hi.w;
          dst[0] = a0;  dst[1] = a1;
        }
      }
    }
    __syncthreads();  // order passes; final one also drains fo DMA
  }

  // ---------------- Phase 4: output projection ----------------
  const int o0 = c * 32 + rg * 4;
  float4 a2[8];
#pragma unroll
  for (int kk = 0; kk < 8; ++kk) a2[kk] = make_float4(0.f, 0.f, 0.f, 0.f);

#pragma unroll 4
  for (int r = 0; r < Rr; ++r) {
    const float4 m0 = *(const float4*)&pT[r][8 * bg];
    const float4 m1 = *(const float4*)&pT[r][8 * bg + 4];
    const float4 f  = *(const float4*)(Sbuf + r * Dd + o0);
    a2[0].x = fmaf(m0.x, f.x, a2[0].x); a2[0].y = fmaf(m0.x, f.y, a2[0].y);
    a2[0].z = fmaf(m0.x, f.z, a2[0].z); a2[0].w = fmaf(m0.x, f.w, a2[0].w);
    a2[1].x = fmaf(m0.y, f.x, a2[1].x); a2[1].y = fmaf(m0.y, f.y, a2[1].y);
    a2[1].z = fmaf(m0.y, f.z, a2[1].z); a2[1].w = fmaf(m0.y, f.w, a2[1].w);
    a2[2].x = fmaf(m0.z, f.x, a2[2].x); a2[2].y = fmaf(m0.z, f.y, a2[2].y);
    a2[2].z = fmaf(m0.z, f.z, a2[2].z); a2[2].w = fmaf(m0.z, f.w, a2[2].w);
    a2[3].x = fmaf(m0.w, f.x, a2[3].x); a2[3].y = fmaf(m0.w, f.y, a2[3].y);
    a2[3].z = fmaf(m0.w, f.z, a2[3].z); a2[3].w = fmaf(m0.w, f.w, a2[3].w);
    a2[4].x = fmaf(m1.x, f.x, a2[4].x); a2[4].y = fmaf(m1.x, f.y, a2[4].y);
    a2[4].z = fmaf(m1.x, f.z, a2[4].z); a2[4].w = fmaf(m1.x, f.w, a2[4].w);
    a2[5].x = fmaf(m1.y, f.x, a2[5].x); a2[5].y = fmaf(m1.y, f.y, a2[5].y);
    a2[5].z = fmaf(m1.y, f.z, a2[5].z); a2[5].w = fmaf(m1.y, f.w, a2[5].w);
    a2[6].x = fmaf(m1.z, f.x, a2[6].x); a2[6].y = fmaf(m1.z, f.y, a2[6].y);
    a2[6].z = fmaf(m1.z, f.z, a2[6].z); a2[6].w = fmaf(m1.z, f.w, a2[6].w);
    a2[7].x = fmaf(m1.w, f.x, a2[7].x); a2[7].y = fmaf(m1.w, f.y, a2[7].y);
    a2[7].z = fmaf(m1.w, f.z, a2[7].z); a2[7].w = fmaf(m1.w, f.w, a2[7].w);
  }

  // ---------------- epilogue: residual (global re-read) + store ---------
#pragma unroll
  for (int kk = 0; kk < 8; ++kk) {
    const int b = 8 * bg + kk;
    const float* xb = x + (((size_t)b * Nn + n) * Cc) * Dd + o0;
    float4 t0 = *(const float4*)(xb);
    float4 t1 = *(const float4*)(xb + Dd);
    float4 t2 = *(const float4*)(xb + 2 * Dd);
    float4 t3 = *(const float4*)(xb + 3 * Dd);
    float4 v;
    v.x = a2[kk].x + 0.25f * (t0.x + t1.x + t2.x + t3.x);
    v.y = a2[kk].y + 0.25f * (t0.y + t1.y + t2.y + t3.y);
    v.z = a2[kk].z + 0.25f * (t0.z + t1.z + t2.z + t3.z);
    v.w = a2[kk].w + 0.25f * (t0.w + t1.w + t2.w + t3.w);
    *(float4*)(out + ((size_t)b * Nn + n) * Dd + o0) = v;
  }
}

extern "C" void kernel_launch(void* const* d_in, const int* in_sizes, int n_in,
                              void* d_out, int out_size, void* d_ws, size_t ws_size,
                              hipStream_t stream) {
  const float* x          = (const float*)d_in[0];
  const float* factors    = (const float*)d_in[1];
  const float* factor_out = (const float*)d_in[2];
  const float* gain       = (const float*)d_in[3];
  float* out              = (float*)d_out;
  hipLaunchKernelGGL(cpquad_kernel, dim3(Nn), dim3(256), 0, stream,
                     x, factors, factor_out, gain, out);
}